// Round 9
// baseline (241.685 us; speedup 1.0000x reference)
//
#include <hip/hip_runtime.h>
#include <math.h>

#define THREADS 256
#define GT 512                     // gram kernel block size (8 waves)
#define BM 128
#define GBK 64
#define EPSV 1e-5f
#define C1E 11.023176380641601f    // e^2.4
#define C2E 9.025013499434122f     // e^2.2

typedef short bf16x8 __attribute__((ext_vector_type(8)));   // 8 bf16 = 16 B
typedef float f32x4 __attribute__((ext_vector_type(4)));

// RNE float -> bf16 bit pattern
__device__ __forceinline__ unsigned short f2bf(float f) {
    union { float f; unsigned int u; } a; a.f = f;
    unsigned int r = a.u + 0x7FFFu + ((a.u >> 16) & 1u);
    return (unsigned short)(r >> 16);
}

#define GLDS16(g, l)                                                          \
    __builtin_amdgcn_global_load_lds(                                         \
        (const __attribute__((address_space(1))) unsigned int*)(g),           \
        (__attribute__((address_space(3))) unsigned int*)(l), 16, 0, 0)

// ---------------------------------------------------------------------------
// Kernel A: fp32 -> bf16 convert + per-row inv L2 norm.
// ---------------------------------------------------------------------------
__global__ void conv_norm_kernel(const float* __restrict__ x,
                                 unsigned short* __restrict__ xb,
                                 float* __restrict__ inv_norm, int D) {
    const int row = blockIdx.x;
    const float4* x4 = (const float4*)(x + (size_t)row * D);
    ushort4* out4 = (ushort4*)(xb + (size_t)row * D);
    const int nf4 = D >> 2;
    float s = 0.f;
    for (int i = threadIdx.x; i < nf4; i += THREADS) {
        float4 v = x4[i];
        s += v.x * v.x + v.y * v.y + v.z * v.z + v.w * v.w;
        ushort4 o;
        o.x = f2bf(v.x); o.y = f2bf(v.y); o.z = f2bf(v.z); o.w = f2bf(v.w);
        out4[i] = o;
    }
#pragma unroll
    for (int off = 32; off > 0; off >>= 1) s += __shfl_down(s, off, 64);
    __shared__ float red[THREADS / 64];
    if ((threadIdx.x & 63) == 0) red[threadIdx.x >> 6] = s;
    __syncthreads();
    if (threadIdx.x == 0) {
        float tot = 0.f;
#pragma unroll
        for (int w = 0; w < THREADS / 64; ++w) tot += red[w];
        inv_norm[row] = 1.0f / fmaxf(sqrtf(tot), 1e-12f);
    }
}

// Plain inv-norm (fallback path).
__global__ void row_inv_norm_kernel(const float* __restrict__ x,
                                    float* __restrict__ inv_norm, int D) {
    const int row = blockIdx.x;
    const float4* x4 = (const float4*)(x + (size_t)row * D);
    const int nf4 = D >> 2;
    float s = 0.f;
    for (int i = threadIdx.x; i < nf4; i += THREADS) {
        float4 v = x4[i];
        s += v.x * v.x + v.y * v.y + v.z * v.z + v.w * v.w;
    }
#pragma unroll
    for (int off = 32; off > 0; off >>= 1) s += __shfl_down(s, off, 64);
    __shared__ float red[THREADS / 64];
    if ((threadIdx.x & 63) == 0) red[threadIdx.x >> 6] = s;
    __syncthreads();
    if (threadIdx.x == 0) {
        float tot = 0.f;
#pragma unroll
        for (int w = 0; w < THREADS / 64; ++w) tot += red[w];
        inv_norm[row] = 1.0f / fmaxf(sqrtf(tot), 1e-12f);
    }
}

// ---------------------------------------------------------------------------
// Kernel B: SYMMETRIC bf16 Gram (128x128 tile, BK=64, 8 waves) + fused loss.
// R9 changes vs R8 (which ran 2 blocks/CU at 12.6% occupancy, latency-bound):
//  - 512-thread blocks: wave grid 2x4 (wave = 64 rows x 32 cols, 8 MFMAs/k-
//    step) -> 16 waves/CU at the same 2 blocks/CU.
//  - BK=64: half the barrier/vmcnt drains; 16 MFMAs + 12 ds_read_b128/iter.
//  - XCD band swizzle tk' = (tk&7)*T/8 + tk>>3: each XCD gets a contiguous
//    triangle band -> B-rows L2-resident.
//  - Epilogue partials combined across waves in LDS (reuse As/Bs): pr/pc are
//    1 slice/tile (ws 25.4 -> 21.1 MB).
// LDS chunk swizzle: chunk (row,q) of the 8-chunk row stored at q^(row&7);
// applied on the glds SOURCE index (dst must be wave-uniform + lane*16).
// vals: 0 s_pos_intra 1 cnt_pi 2 s_pos_cross 3 cnt_pc
//       4 DE_neg_intra 5 E_neg_intra 6 DE_neg_cross 7 E_neg_cross
//       (E = sum exp(-d), DE = sum d*exp(-d); e^alpha folded in finalize)
// ---------------------------------------------------------------------------
__launch_bounds__(GT, 4)   // 4 waves/SIMD = 2 blocks/CU co-resident, VGPR<=128
__global__ void gram_sym_kernel(const unsigned short* __restrict__ xb,
                                const int* __restrict__ targets,
                                const int* __restrict__ sub,
                                const float* __restrict__ inv_norm,
                                float* __restrict__ pr,
                                float* __restrict__ pc,
                                int D, int nbx) {
    __shared__ unsigned short As[BM * GBK];   // 16 KB
    __shared__ unsigned short Bs[BM * GBK];   // 16 KB

    // XCD band swizzle, then triangular decode tk = bx*(bx+1)/2 + by.
    const int T = gridDim.x;
    int tk = blockIdx.x;
    if ((T & 7) == 0) tk = (tk & 7) * (T >> 3) + (tk >> 3);
    int bx = (int)((sqrtf(8.0f * tk + 1.0f) - 1.0f) * 0.5f);
    while ((bx + 1) * (bx + 2) / 2 <= tk) ++bx;
    while (bx * (bx + 1) / 2 > tk) --bx;
    const int by = tk - bx * (bx + 1) / 2;

    const int tid = threadIdx.x;
    const int w = tid >> 6;          // wave 0..7
    const int lane = tid & 63;
    const int wm2 = w & 1;           // row-half (64 rows)
    const int wn4 = w >> 1;          // col-quarter (32 cols)
    const int quad = lane >> 4;
    const int cl = lane & 15;

    const int rowA0 = by * BM;
    const int colB0 = bx * BM;
    const unsigned short* Abase = xb + (size_t)rowA0 * D;
    const unsigned short* Bbase = xb + (size_t)colB0 * D;

    // glds staging: tile = 128 rows x 8 chunks = 1024 chunks of 16B.
    // Wave w issue l covers LDS chunks l*512 + w*64 + lane (contiguous 1KB).
    const int ca0 = w * 64 + lane;
    const int ca1 = 512 + w * 64 + lane;
    const int r0 = ca0 >> 3, q0 = (ca0 & 7) ^ (r0 & 7);
    const int r1 = ca1 >> 3, q1 = (ca1 & 7) ^ (r1 & 7);
    const unsigned short* sA0 = Abase + (size_t)r0 * D + q0 * 8;
    const unsigned short* sA1 = Abase + (size_t)r1 * D + q1 * 8;
    const unsigned short* sB0 = Bbase + (size_t)r0 * D + q0 * 8;
    const unsigned short* sB1 = Bbase + (size_t)r1 * D + q1 * 8;
    unsigned short* dA0 = As + (w * 64) * 8;          // wave-uniform bases
    unsigned short* dA1 = As + (512 + w * 64) * 8;
    unsigned short* dB0 = Bs + (w * 64) * 8;
    unsigned short* dB1 = Bs + (512 + w * 64) * 8;

    f32x4 accv[4][2];
#pragma unroll
    for (int i = 0; i < 4; ++i)
#pragma unroll
        for (int j = 0; j < 2; ++j) accv[i][j] = (f32x4)(0.f);

    // Fragment offsets (shorts): row r, k-chunk (ks*4+quad) ^ (r&7).
    int aoff[4][2], boff[2][2];
#pragma unroll
    for (int mi = 0; mi < 4; ++mi) {
        const int ar = wm2 * 64 + mi * 16 + cl;
#pragma unroll
        for (int ks = 0; ks < 2; ++ks)
            aoff[mi][ks] = ar * GBK + (((ks << 2) | quad) ^ (ar & 7)) * 8;
    }
#pragma unroll
    for (int ni = 0; ni < 2; ++ni) {
        const int br = wn4 * 32 + ni * 16 + cl;
#pragma unroll
        for (int ks = 0; ks < 2; ++ks)
            boff[ni][ks] = br * GBK + (((ks << 2) | quad) ^ (br & 7)) * 8;
    }

    for (int kb = 0; kb < D; kb += GBK) {
        GLDS16(sA0 + kb, dA0);
        GLDS16(sA1 + kb, dA1);
        GLDS16(sB0 + kb, dB0);
        GLDS16(sB1 + kb, dB1);
        __syncthreads();   // drains vmcnt: tiles in LDS

#pragma unroll
        for (int ks = 0; ks < 2; ++ks) {
            bf16x8 af[4], bfv[2];
#pragma unroll
            for (int mi = 0; mi < 4; ++mi)
                af[mi] = *(const bf16x8*)&As[aoff[mi][ks]];
#pragma unroll
            for (int ni = 0; ni < 2; ++ni)
                bfv[ni] = *(const bf16x8*)&Bs[boff[ni][ks]];
#pragma unroll
            for (int mi = 0; mi < 4; ++mi)
#pragma unroll
                for (int ni = 0; ni < 2; ++ni)
                    accv[mi][ni] = __builtin_amdgcn_mfma_f32_16x16x32_bf16(
                        af[mi], bfv[ni], accv[mi][ni], 0, 0, 0);
        }
        __syncthreads();   // tiles consumed
    }

    // ------------------- epilogue (single pass) -------------------
    // C/D map: col = cl, row = quad*4 + reg.
    int tj[2], sj[2];
    float ivj[2];
#pragma unroll
    for (int ni = 0; ni < 2; ++ni) {
        const int gc = colB0 + wn4 * 32 + ni * 16 + cl;
        tj[ni] = targets[gc];
        sj[ni] = sub[gc];
        ivj[ni] = inv_norm[gc];
    }

    // LDS reuse for cross-wave partial combine (tiles already consumed):
    float* rowbuf = (float*)As;   // [128 rows][4 wn4][8]  = 16 KB
    float* colbuf = (float*)Bs;   // [128 cols][2 wm2][8]  =  8 KB

    float cacc[2][8];
#pragma unroll
    for (int ni = 0; ni < 2; ++ni)
#pragma unroll
        for (int k2 = 0; k2 < 8; ++k2) cacc[ni][k2] = 0.f;

#pragma unroll
    for (int mi = 0; mi < 4; ++mi) {
#pragma unroll
        for (int r = 0; r < 4; ++r) {
            const int rloc = wm2 * 64 + mi * 16 + quad * 4 + r;
            const int gi = rowA0 + rloc;
            const int ti = targets[gi];
            const int si = sub[gi];
            const float si2 = 2.0f * inv_norm[gi];

            float s0 = 0.f, s1 = 0.f, s2 = 0.f, s3 = 0.f;
            float s4 = 0.f, s5 = 0.f, s6 = 0.f, s7 = 0.f;
#pragma unroll
            for (int ni = 0; ni < 2; ++ni) {
                const int gj = colB0 + wn4 * 32 + ni * 16 + cl;
                const float t = accv[mi][ni][r] * si2;
                const float d2 = fmaf(-t, ivj[ni], 2.0f);
                const float dd = sqrtf(fmaxf(d2, 1e-12f));
                const bool same = (ti == tj[ni]);
                const bool intra = (si == sj[ni]);
                const bool pos = same && (gi != gj);
                const bool neg = !same;
                const float mg = intra ? 1.4f : 0.7f;
                const float v = fmaxf(dd - mg, 0.f);
                const float e = __expf(-dd);
                const float de = dd * e;
                const float c0 = (pos && intra) ? v : 0.f;
                const float c1 = (pos && intra) ? 1.f : 0.f;
                const float c2 = (pos && !intra) ? v : 0.f;
                const float c3 = (pos && !intra) ? 1.f : 0.f;
                const float c4 = (neg && intra) ? de : 0.f;
                const float c5 = (neg && intra) ? e : 0.f;
                const float c6 = (neg && !intra) ? de : 0.f;
                const float c7 = (neg && !intra) ? e : 0.f;
                s0 += c0; s1 += c1; s2 += c2; s3 += c3;
                s4 += c4; s5 += c5; s6 += c6; s7 += c7;
                cacc[ni][0] += c0; cacc[ni][1] += c1;
                cacc[ni][2] += c2; cacc[ni][3] += c3;
                cacc[ni][4] += c4; cacc[ni][5] += c5;
                cacc[ni][6] += c6; cacc[ni][7] += c7;
            }
#pragma unroll
            for (int off = 1; off < 16; off <<= 1) {
                s0 += __shfl_xor(s0, off, 64);
                s1 += __shfl_xor(s1, off, 64);
                s2 += __shfl_xor(s2, off, 64);
                s3 += __shfl_xor(s3, off, 64);
                s4 += __shfl_xor(s4, off, 64);
                s5 += __shfl_xor(s5, off, 64);
                s6 += __shfl_xor(s6, off, 64);
                s7 += __shfl_xor(s7, off, 64);
            }
            if (cl == 0) {
                float* dst = rowbuf + ((size_t)rloc * 4 + wn4) * 8;
                float4 p0 = {s0, s1, s2, s3};
                float4 p1 = {s4, s5, s6, s7};
                *(float4*)(dst) = p0;
                *(float4*)(dst + 4) = p1;
            }
        }
    }

    // Col partials: reduce cacc over the 4 quads, stash per-wm2 in LDS.
#pragma unroll
    for (int ni = 0; ni < 2; ++ni) {
#pragma unroll
        for (int k2 = 0; k2 < 8; ++k2) {
            float v = cacc[ni][k2];
            v += __shfl_xor(v, 16, 64);
            v += __shfl_xor(v, 32, 64);
            cacc[ni][k2] = v;
        }
        if (lane < 16) {
            const int colloc = wn4 * 32 + ni * 16 + lane;
            float* dst = colbuf + ((size_t)colloc * 2 + wm2) * 8;
            float4 p0 = {cacc[ni][0], cacc[ni][1], cacc[ni][2], cacc[ni][3]};
            float4 p1 = {cacc[ni][4], cacc[ni][5], cacc[ni][6], cacc[ni][7]};
            *(float4*)(dst) = p0;
            *(float4*)(dst + 4) = p1;
        }
    }
    __syncthreads();

    // Cross-wave combine + store (coalesced, one slice per tile per side).
    const float om = (bx == by) ? 0.f : 1.f;   // diag: zero col side
    for (int u = tid; u < 128 * 8; u += GT) {
        const int row = u >> 3, k2 = u & 7;
        const float* rb = rowbuf + ((size_t)row * 4) * 8 + k2;
        pr[((size_t)tk * 128 + row) * 8 + k2] =
            rb[0] + rb[8] + rb[16] + rb[24];
        const float* cb = colbuf + ((size_t)row * 2) * 8 + k2;
        pc[((size_t)tk * 128 + row) * 8 + k2] = om * (cb[0] + cb[8]);
    }
}

// ---------------------------------------------------------------------------
// Kernel C: gather (nbx-B) row-slices + (B+1) col-slices per row, combine.
// Block = 16 rows x 16 slice-threads.
// ---------------------------------------------------------------------------
__global__ void finalize_sym_kernel(const float* __restrict__ pr,
                                    const float* __restrict__ pc,
                                    float* __restrict__ out, int N, int nbx) {
    const int tid = threadIdx.x;
    const int rloc16 = tid >> 4;   // row within block, 0..15
    const int st = tid & 15;       // slice-thread
    const int i = blockIdx.x * 16 + rloc16;
    const int B = i >> 7;          // row's 128-block
    const int rl = i & 127;

    float a0 = 0.f, a1 = 0.f, a2 = 0.f, a3 = 0.f;
    float a4 = 0.f, a5 = 0.f, a6 = 0.f, a7 = 0.f;
    // Row-side: tiles (bxx, B), bxx = B..nbx-1.
    for (int s = st; s < nbx - B; s += 16) {
        const int bxx = B + s;
        const int t = bxx * (bxx + 1) / 2 + B;
        const float* base = pr + ((size_t)t * 128 + rl) * 8;
        float4 u0 = *(const float4*)(base);
        float4 u1 = *(const float4*)(base + 4);
        a0 += u0.x; a1 += u0.y; a2 += u0.z; a3 += u0.w;
        a4 += u1.x; a5 += u1.y; a6 += u1.z; a7 += u1.w;
    }
    // Col-side: tiles (B, by2), by2 = 0..B (diag slice stored as zeros).
    for (int s = st; s <= B; s += 16) {
        const int t = B * (B + 1) / 2 + s;
        const float* base = pc + ((size_t)t * 128 + rl) * 8;
        float4 u0 = *(const float4*)(base);
        float4 u1 = *(const float4*)(base + 4);
        a0 += u0.x; a1 += u0.y; a2 += u0.z; a3 += u0.w;
        a4 += u1.x; a5 += u1.y; a6 += u1.z; a7 += u1.w;
    }
#pragma unroll
    for (int off = 1; off < 16; off <<= 1) {
        a0 += __shfl_xor(a0, off, 64);
        a1 += __shfl_xor(a1, off, 64);
        a2 += __shfl_xor(a2, off, 64);
        a3 += __shfl_xor(a3, off, 64);
        a4 += __shfl_xor(a4, off, 64);
        a5 += __shfl_xor(a5, off, 64);
        a6 += __shfl_xor(a6, off, 64);
        a7 += __shfl_xor(a7, off, 64);
    }
    __shared__ float lred[16];
    if (st == 0) {
        const float l = a0 / (a1 + EPSV) + a2 / (a3 + EPSV)
            + (C1E * fmaf(2.4f, a5, -a4)) / (C1E * a5 + EPSV)
            + (C2E * fmaf(2.2f, a7, -a6)) / (C2E * a7 + EPSV);
        lred[rloc16] = l;
    }
    __syncthreads();
    if (tid == 0) {
        float tot = 0.f;
#pragma unroll
        for (int k2 = 0; k2 < 16; ++k2) tot += lred[k2];
        atomicAdd(out, tot / (float)N);
    }
}

// ---------------------------------------------------------------------------
// Fallback path (144 KB ws): fp32 tile GEMM + atomic epilogue (R1, known-good)
// ---------------------------------------------------------------------------
__launch_bounds__(THREADS, 2)
__global__ void dist_loss_kernel(const float* __restrict__ x,
                                 const int* __restrict__ targets,
                                 const int* __restrict__ sub,
                                 const float* __restrict__ inv_norm,
                                 float* __restrict__ acc,
                                 int N, int D) {
    __shared__ float Asf[16][128];
    __shared__ float Bsf[16][128];

    const int nbx = N / 128;
    const int bx = blockIdx.x % nbx;
    const int by = blockIdx.x / nbx;
    const int tid = threadIdx.x;
    const int tx = tid & 15;
    const int ty = tid >> 4;
    const int rowA0 = by * 128;
    const int colB0 = bx * 128;
    const float* Abase = x + (size_t)rowA0 * D;
    const float* Bbase = x + (size_t)colB0 * D;

    float accv[8][8];
#pragma unroll
    for (int r = 0; r < 8; ++r)
#pragma unroll
        for (int c = 0; c < 8; ++c) accv[r][c] = 0.f;

    for (int kb = 0; kb < D; kb += 16) {
#pragma unroll
        for (int l = 0; l < 2; ++l) {
            const int f = tid + l * THREADS;
            const int row = f >> 2;
            const int kq = (f & 3) << 2;
            float4 va = *(const float4*)(Abase + (size_t)row * D + kb + kq);
            float4 vb = *(const float4*)(Bbase + (size_t)row * D + kb + kq);
            Asf[kq + 0][row] = va.x; Asf[kq + 1][row] = va.y;
            Asf[kq + 2][row] = va.z; Asf[kq + 3][row] = va.w;
            Bsf[kq + 0][row] = vb.x; Bsf[kq + 1][row] = vb.y;
            Bsf[kq + 2][row] = vb.z; Bsf[kq + 3][row] = vb.w;
        }
        __syncthreads();
#pragma unroll
        for (int k = 0; k < 16; ++k) {
            float4 a0 = *(const float4*)&Asf[k][ty * 8];
            float4 a1 = *(const float4*)&Asf[k][ty * 8 + 4];
            float4 b0 = *(const float4*)&Bsf[k][tx * 8];
            float4 b1 = *(const float4*)&Bsf[k][tx * 8 + 4];
            float ar[8] = {a0.x, a0.y, a0.z, a0.w, a1.x, a1.y, a1.z, a1.w};
            float br[8] = {b0.x, b0.y, b0.z, b0.w, b1.x, b1.y, b1.z, b1.w};
#pragma unroll
            for (int r = 0; r < 8; ++r)
#pragma unroll
                for (int c = 0; c < 8; ++c)
                    accv[r][c] = fmaf(ar[r], br[c], accv[r][c]);
        }
        __syncthreads();
    }

    const int row_base = rowA0 + ty * 8;
    const int col_base = colB0 + tx * 8;
    int tjc[8], sjc[8];
    float invj[8];
#pragma unroll
    for (int c = 0; c < 8; ++c) {
        tjc[c] = targets[col_base + c];
        sjc[c] = sub[col_base + c];
        invj[c] = inv_norm[col_base + c];
    }
#pragma unroll
    for (int r = 0; r < 8; ++r) {
        const int gi = row_base + r;
        const int ti = targets[gi];
        const int si = sub[gi];
        const float invi = inv_norm[gi];
        float s0 = 0.f, s1 = 0.f, s2 = 0.f, s3 = 0.f;
        float s4 = 0.f, s5 = 0.f, s6 = 0.f, s7 = 0.f;
#pragma unroll
        for (int c = 0; c < 8; ++c) {
            const int gj = col_base + c;
            const float dot = accv[r][c] * invi * invj[c];
            const float dd = sqrtf(fmaxf(2.f - 2.f * dot, 1e-12f));
            const bool same = (ti == tjc[c]);
            const bool intra = (si == sjc[c]);
            const bool pos = same && (gi != gj);
            const bool neg = !same;
            const float df = (intra ? 2.4f : 2.2f) - dd;
            const float wgt = __expf(df);
            const float v = fmaxf(dd - (intra ? 1.4f : 0.7f), 0.f);
            if (pos && intra)  { s0 += v; s1 += 1.f; }
            if (pos && !intra) { s2 += v; s3 += 1.f; }
            if (neg && intra)  { s4 += df * wgt; s5 += wgt; }
            if (neg && !intra) { s6 += df * wgt; s7 += wgt; }
        }
#pragma unroll
        for (int off = 1; off < 16; off <<= 1) {
            s0 += __shfl_xor(s0, off, 64);
            s1 += __shfl_xor(s1, off, 64);
            s2 += __shfl_xor(s2, off, 64);
            s3 += __shfl_xor(s3, off, 64);
            s4 += __shfl_xor(s4, off, 64);
            s5 += __shfl_xor(s5, off, 64);
            s6 += __shfl_xor(s6, off, 64);
            s7 += __shfl_xor(s7, off, 64);
        }
        if (tx == 0) {
            float* a = acc + (size_t)gi * 8;
            atomicAdd(a + 0, s0); atomicAdd(a + 1, s1);
            atomicAdd(a + 2, s2); atomicAdd(a + 3, s3);
            atomicAdd(a + 4, s4); atomicAdd(a + 5, s5);
            atomicAdd(a + 6, s6); atomicAdd(a + 7, s7);
        }
    }
}

__global__ void finalize_kernel(const float* __restrict__ acc,
                                float* __restrict__ out, int N) {
    float s = 0.f;
    for (int i = threadIdx.x; i < N; i += THREADS) {
        const float* a = acc + (size_t)i * 8;
        s += a[0] / (a[1] + EPSV) + a[2] / (a[3] + EPSV)
           + a[4] / (a[5] + EPSV) + a[6] / (a[7] + EPSV);
    }
#pragma unroll
    for (int off = 32; off > 0; off >>= 1) s += __shfl_down(s, off, 64);
    __shared__ float red[THREADS / 64];
    if ((threadIdx.x & 63) == 0) red[threadIdx.x >> 6] = s;
    __syncthreads();
    if (threadIdx.x == 0) {
        float tot = 0.f;
#pragma unroll
        for (int w = 0; w < THREADS / 64; ++w) tot += red[w];
        out[0] = tot / (float)N;
    }
}

// ---------------------------------------------------------------------------
extern "C" void kernel_launch(void* const* d_in, const int* in_sizes, int n_in,
                              void* d_out, int out_size, void* d_ws, size_t ws_size,
                              hipStream_t stream) {
    const float* x = (const float*)d_in[0];
    const int* targets = (const int*)d_in[1];
    const int* sub = (const int*)d_in[2];
    const int N = in_sizes[1];
    const int D = in_sizes[0] / N;

    const int nbx = N / BM;
    const int T = nbx * (nbx + 1) / 2;
    const size_t sliceB = (size_t)T * 128 * 8 * sizeof(float);
    const size_t need = (size_t)N * 4 + (size_t)N * D * 2 + 2 * sliceB;

    if (ws_size >= need) {
        float* inv_norm = (float*)d_ws;                       // N floats
        unsigned short* xb = (unsigned short*)(inv_norm + N); // N*D bf16
        float* pr = (float*)((char*)d_ws + (size_t)N * 4 + (size_t)N * D * 2);
        float* pc = pr + (size_t)T * 128 * 8;

        hipMemsetAsync(d_out, 0, sizeof(float), stream);
        conv_norm_kernel<<<N, THREADS, 0, stream>>>(x, xb, inv_norm, D);
        gram_sym_kernel<<<T, GT, 0, stream>>>(xb, targets, sub,
                                              inv_norm, pr, pc, D, nbx);
        finalize_sym_kernel<<<N / 16, THREADS, 0, stream>>>(
            pr, pc, (float*)d_out, N, nbx);
    } else {
        // Fallback (144 KB ws): fp32 path, known-good from round 1.
        float* inv_norm = (float*)d_ws;
        float* acc = inv_norm + N;
        hipMemsetAsync(acc, 0, (size_t)N * 8 * sizeof(float), stream);
        row_inv_norm_kernel<<<N, THREADS, 0, stream>>>(x, inv_norm, D);
        dist_loss_kernel<<<nbx * nbx, THREADS, 0, stream>>>(
            x, targets, sub, inv_norm, acc, N, D);
        finalize_kernel<<<1, THREADS, 0, stream>>>(acc, (float*)d_out, N);
    }
}

// Round 10
// 198.494 us; speedup vs baseline: 1.2176x; 1.2176x over previous
//
#include <hip/hip_runtime.h>
#include <math.h>

#define THREADS 256
#define BM 128
#define BK 32
#define EPSV 1e-5f
#define C1E 11.023176380641601f   // e^2.4
#define C2E 9.025013499434122f    // e^2.2

typedef short bf16x8 __attribute__((ext_vector_type(8)));   // 8 bf16 = 16 B
typedef float f32x4 __attribute__((ext_vector_type(4)));

// RNE float -> bf16 bit pattern (no union: avoid any scratch-alloc risk)
__device__ __forceinline__ unsigned short f2bf(float f) {
    unsigned int u = __float_as_uint(f);
    u += 0x7FFFu + ((u >> 16) & 1u);
    return (unsigned short)(u >> 16);
}

#define GLDS16(g, l)                                                          \
    __builtin_amdgcn_global_load_lds(                                         \
        (const __attribute__((address_space(1))) unsigned int*)(g),           \
        (__attribute__((address_space(3))) unsigned int*)(l), 16, 0, 0)

// ---------------------------------------------------------------------------
// Kernel A: fp32 -> bf16 convert + per-row inv L2 norm.
// ---------------------------------------------------------------------------
__global__ void conv_norm_kernel(const float* __restrict__ x,
                                 unsigned short* __restrict__ xb,
                                 float* __restrict__ inv_norm, int D) {
    const int row = blockIdx.x;
    const float4* x4 = (const float4*)(x + (size_t)row * D);
    ushort4* out4 = (ushort4*)(xb + (size_t)row * D);
    const int nf4 = D >> 2;
    float s = 0.f;
    for (int i = threadIdx.x; i < nf4; i += THREADS) {
        float4 v = x4[i];
        s += v.x * v.x + v.y * v.y + v.z * v.z + v.w * v.w;
        ushort4 o;
        o.x = f2bf(v.x); o.y = f2bf(v.y); o.z = f2bf(v.z); o.w = f2bf(v.w);
        out4[i] = o;
    }
#pragma unroll
    for (int off = 32; off > 0; off >>= 1) s += __shfl_down(s, off, 64);
    __shared__ float red[THREADS / 64];
    if ((threadIdx.x & 63) == 0) red[threadIdx.x >> 6] = s;
    __syncthreads();
    if (threadIdx.x == 0) {
        float tot = 0.f;
#pragma unroll
        for (int w = 0; w < THREADS / 64; ++w) tot += red[w];
        inv_norm[row] = 1.0f / fmaxf(sqrtf(tot), 1e-12f);
    }
}

// Plain inv-norm (fallback path).
__global__ void row_inv_norm_kernel(const float* __restrict__ x,
                                    float* __restrict__ inv_norm, int D) {
    const int row = blockIdx.x;
    const float4* x4 = (const float4*)(x + (size_t)row * D);
    const int nf4 = D >> 2;
    float s = 0.f;
    for (int i = threadIdx.x; i < nf4; i += THREADS) {
        float4 v = x4[i];
        s += v.x * v.x + v.y * v.y + v.z * v.z + v.w * v.w;
    }
#pragma unroll
    for (int off = 32; off > 0; off >>= 1) s += __shfl_down(s, off, 64);
    __shared__ float red[THREADS / 64];
    if ((threadIdx.x & 63) == 0) red[threadIdx.x >> 6] = s;
    __syncthreads();
    if (threadIdx.x == 0) {
        float tot = 0.f;
#pragma unroll
        for (int w = 0; w < THREADS / 64; ++w) tot += red[w];
        inv_norm[row] = 1.0f / fmaxf(sqrtf(tot), 1e-12f);
    }
}

// ---------------------------------------------------------------------------
// Kernel B: SYMMETRIC bf16 Gram tile + two-pass epilogue (R8 base) with a
// DOUBLE-BUFFERED glds pipeline: tile k+1's global_load_lds is issued into
// buf^1 BEFORE the MFMAs on tile k, so by the time the barrier's vmcnt(0)
// drain runs, the loads have had a full compute phase (~700 cyc) in flight
// (L2 latency ~250 cyc) -> drain ~free. This attacks R8's serial
// glds -> drain -> compute chain (R8: 4400 cyc/K-iter/CU vs ~600 floor).
// Hazards: buf[cur] reads complete before the barrier preceding any
// overwrite of buf[cur] (overwrite happens next iteration, post-barrier).
// vals: 0 s_pos_intra 1 cnt_pi 2 s_pos_cross 3 cnt_pc
//       4 DE_neg_intra 5 E_neg_intra 6 DE_neg_cross 7 E_neg_cross
//       (E = sum exp(-d), DE = sum d*exp(-d); e^alpha folded in finalize)
// ---------------------------------------------------------------------------
__launch_bounds__(THREADS, 2)
__global__ void gram_sym_kernel(const unsigned short* __restrict__ xb,
                                const int* __restrict__ targets,
                                const int* __restrict__ sub,
                                const float* __restrict__ inv_norm,
                                float* __restrict__ pr,
                                float* __restrict__ pc,
                                int D) {
    __shared__ unsigned short As[2][BM * BK];   // 2 x 8 KB
    __shared__ unsigned short Bs[2][BM * BK];   // 2 x 8 KB

    // Triangular decode: tk = bx*(bx+1)/2 + by, by <= bx.
    const int tk = blockIdx.x;
    int bx = (int)((sqrtf(8.0f * tk + 1.0f) - 1.0f) * 0.5f);
    while ((bx + 1) * (bx + 2) / 2 <= tk) ++bx;
    while (bx * (bx + 1) / 2 > tk) --bx;
    const int by = tk - bx * (bx + 1) / 2;

    const int tid = threadIdx.x;
    const int w = tid >> 6;          // wave 0..3
    const int lane = tid & 63;
    const int wm = w & 1;            // row-half
    const int wn = w >> 1;           // col-half
    const int quad = lane >> 4;
    const int cl = lane & 15;

    const int rowA0 = by * BM;
    const int colB0 = bx * BM;
    const unsigned short* Abase = xb + (size_t)rowA0 * D;
    const unsigned short* Bbase = xb + (size_t)colB0 * D;

    // glds staging: 512 chunks of 16B per tile. Wave w, issue l covers LDS
    // chunks (l*256 + w*64 + lane); source chunk index is XOR-swizzled.
    const int ca0 = w * 64 + lane;
    const int ca1 = 256 + w * 64 + lane;
    const int r0 = ca0 >> 2, q0 = (ca0 & 3) ^ ((r0 >> 1) & 3);
    const int r1 = ca1 >> 2, q1 = (ca1 & 3) ^ ((r1 >> 1) & 3);
    const unsigned short* sA0 = Abase + (size_t)r0 * D + q0 * 8;
    const unsigned short* sA1 = Abase + (size_t)r1 * D + q1 * 8;
    const unsigned short* sB0 = Bbase + (size_t)r0 * D + q0 * 8;
    const unsigned short* sB1 = Bbase + (size_t)r1 * D + q1 * 8;
    const int dof0 = (w * 64) * 8;            // wave-uniform LDS offsets
    const int dof1 = (256 + w * 64) * 8;

    f32x4 accv[4][4];
#pragma unroll
    for (int i = 0; i < 4; ++i)
#pragma unroll
        for (int j = 0; j < 4; ++j) accv[i][j] = (f32x4)(0.f);

    // Fragment read offsets (tile-local), swizzled: q' = quad ^ ((row>>1)&3).
    int aoff[4], boff[4];
#pragma unroll
    for (int f = 0; f < 4; ++f) {
        const int ar = wm * 64 + f * 16 + cl;
        aoff[f] = ar * BK + (quad ^ ((ar >> 1) & 3)) * 8;
        const int br = wn * 64 + f * 16 + cl;
        boff[f] = br * BK + (quad ^ ((br >> 1) & 3)) * 8;
    }

    const int nIter = D / BK;

    // Prologue: stage tile 0 into buf 0 (one unavoidable full drain).
    GLDS16(sA0, &As[0][dof0]);
    GLDS16(sA1, &As[0][dof1]);
    GLDS16(sB0, &Bs[0][dof0]);
    GLDS16(sB1, &Bs[0][dof1]);
    __syncthreads();

    for (int it = 0; it < nIter; ++it) {
        const int cur = it & 1;
        const int nxt = cur ^ 1;

        // Prefetch tile it+1 into the other buffer BEFORE computing tile it.
        if (it + 1 < nIter) {
            const int kb = (it + 1) * BK;
            GLDS16(sA0 + kb, &As[nxt][dof0]);
            GLDS16(sA1 + kb, &As[nxt][dof1]);
            GLDS16(sB0 + kb, &Bs[nxt][dof0]);
            GLDS16(sB1 + kb, &Bs[nxt][dof1]);
        }

        bf16x8 af[4], bfv[4];
#pragma unroll
        for (int f = 0; f < 4; ++f) {
            af[f] = *(const bf16x8*)&As[cur][aoff[f]];
            bfv[f] = *(const bf16x8*)&Bs[cur][boff[f]];
        }
#pragma unroll
        for (int mi = 0; mi < 4; ++mi)
#pragma unroll
            for (int ni = 0; ni < 4; ++ni)
                accv[mi][ni] = __builtin_amdgcn_mfma_f32_16x16x32_bf16(
                    af[mi], bfv[ni], accv[mi][ni], 0, 0, 0);

        __syncthreads();   // drains prefetch (had a full compute phase in
                           // flight) + guards buf[cur] reuse next iteration
    }

    // ---------------- epilogue pass 1: dd + row partials ----------------
    // C/D map: col = cl, row = quad*4 + reg.
    int tj[4], sj[4];
    float ivj[4];
#pragma unroll
    for (int ni = 0; ni < 4; ++ni) {
        const int gc = colB0 + wn * 64 + ni * 16 + cl;
        tj[ni] = targets[gc];
        sj[ni] = sub[gc];
        ivj[ni] = inv_norm[gc];
    }

#pragma unroll
    for (int mi = 0; mi < 4; ++mi) {
#pragma unroll
        for (int r = 0; r < 4; ++r) {
            const int gi = rowA0 + wm * 64 + mi * 16 + quad * 4 + r;
            const int ti = targets[gi];
            const int si = sub[gi];
            const float si2 = 2.0f * inv_norm[gi];

            float s0 = 0.f, s1 = 0.f, s2 = 0.f, s3 = 0.f;
            float s4 = 0.f, s5 = 0.f, s6 = 0.f, s7 = 0.f;
#pragma unroll
            for (int ni = 0; ni < 4; ++ni) {
                const int gj = colB0 + wn * 64 + ni * 16 + cl;
                const float t = accv[mi][ni][r] * si2;
                const float d2 = fmaf(-t, ivj[ni], 2.0f);
                const float dd = sqrtf(fmaxf(d2, 1e-12f));
                accv[mi][ni][r] = dd;          // overwrite: pass 2 reuses
                const bool same = (ti == tj[ni]);
                const bool intra = (si == sj[ni]);
                const bool pos = same && (gi != gj);
                const bool neg = !same;
                const float mg = intra ? 1.4f : 0.7f;
                const float v = fmaxf(dd - mg, 0.f);
                const float e = __expf(-dd);   // e^alpha folded in finalize
                const float de = dd * e;
                if (pos && intra)  { s0 += v;  s1 += 1.f; }
                if (pos && !intra) { s2 += v;  s3 += 1.f; }
                if (neg && intra)  { s4 += de; s5 += e; }
                if (neg && !intra) { s6 += de; s7 += e; }
            }
#pragma unroll
            for (int off = 1; off < 16; off <<= 1) {
                s0 += __shfl_xor(s0, off, 64);
                s1 += __shfl_xor(s1, off, 64);
                s2 += __shfl_xor(s2, off, 64);
                s3 += __shfl_xor(s3, off, 64);
                s4 += __shfl_xor(s4, off, 64);
                s5 += __shfl_xor(s5, off, 64);
                s6 += __shfl_xor(s6, off, 64);
                s7 += __shfl_xor(s7, off, 64);
            }
            if (cl == 0) {
                const int rloc = wm * 64 + mi * 16 + quad * 4 + r;
                float* dst = pr +
                    ((size_t)(blockIdx.x * 2 + wn) * 128 + rloc) * 8;
                float4 p0 = {s0, s1, s2, s3};
                float4 p1 = {s4, s5, s6, s7};
                *(float4*)(dst) = p0;
                *(float4*)(dst + 4) = p1;
            }
        }
    }

    // ---------------- epilogue pass 2: col partials ----------------
    const float om = (bx == by) ? 0.f : 1.f;   // diag tiles: zero col side
#pragma unroll
    for (int ni = 0; ni < 4; ++ni) {
        const int gj = colB0 + wn * 64 + ni * 16 + cl;
        const int tjc = tj[ni];
        const int sjc = sj[ni];
        float s0 = 0.f, s1 = 0.f, s2 = 0.f, s3 = 0.f;
        float s4 = 0.f, s5 = 0.f, s6 = 0.f, s7 = 0.f;
#pragma unroll
        for (int mi = 0; mi < 4; ++mi) {
#pragma unroll
            for (int r = 0; r < 4; ++r) {
                const int gi = rowA0 + wm * 64 + mi * 16 + quad * 4 + r;
                const int ti = targets[gi];     // L1-hot reload
                const int si = sub[gi];
                const float dd = accv[mi][ni][r];
                const bool same = (ti == tjc);
                const bool intra = (si == sjc);
                const bool pos = same && (gi != gj);
                const bool neg = !same;
                const float mg = intra ? 1.4f : 0.7f;
                const float v = fmaxf(dd - mg, 0.f);
                const float e = __expf(-dd);
                const float de = dd * e;
                if (pos && intra)  { s0 += v;  s1 += 1.f; }
                if (pos && !intra) { s2 += v;  s3 += 1.f; }
                if (neg && intra)  { s4 += de; s5 += e; }
                if (neg && !intra) { s6 += de; s7 += e; }
            }
        }
        // Reduce over the 4 quads (row groups): lanes differing in bits 4,5.
        s0 += __shfl_xor(s0, 16, 64); s0 += __shfl_xor(s0, 32, 64);
        s1 += __shfl_xor(s1, 16, 64); s1 += __shfl_xor(s1, 32, 64);
        s2 += __shfl_xor(s2, 16, 64); s2 += __shfl_xor(s2, 32, 64);
        s3 += __shfl_xor(s3, 16, 64); s3 += __shfl_xor(s3, 32, 64);
        s4 += __shfl_xor(s4, 16, 64); s4 += __shfl_xor(s4, 32, 64);
        s5 += __shfl_xor(s5, 16, 64); s5 += __shfl_xor(s5, 32, 64);
        s6 += __shfl_xor(s6, 16, 64); s6 += __shfl_xor(s6, 32, 64);
        s7 += __shfl_xor(s7, 16, 64); s7 += __shfl_xor(s7, 32, 64);
        if (lane < 16) {
            const int colloc = wn * 64 + ni * 16 + lane;
            float* dst = pc +
                ((size_t)(blockIdx.x * 2 + wm) * 128 + colloc) * 8;
            float4 p0 = {s0 * om, s1 * om, s2 * om, s3 * om};
            float4 p1 = {s4 * om, s5 * om, s6 * om, s7 * om};
            *(float4*)(dst) = p0;
            *(float4*)(dst + 4) = p1;
        }
    }
}

// ---------------------------------------------------------------------------
// Kernel C: gather 64 slices per row, combine ratios, global mean.
// Block = 16 rows x 16 slice-threads.
// ---------------------------------------------------------------------------
__global__ void finalize_sym_kernel(const float* __restrict__ pr,
                                    const float* __restrict__ pc,
                                    float* __restrict__ out, int N, int nbx) {
    const int tid = threadIdx.x;
    const int rloc16 = tid >> 4;   // row within block, 0..15
    const int st = tid & 15;       // slice-thread
    const int i = blockIdx.x * 16 + rloc16;
    const int B = i >> 7;          // row's 128-block
    const int rl = i & 127;
    const int nrow = (nbx - B) * 2;   // # row-side slices

    float a0 = 0.f, a1 = 0.f, a2 = 0.f, a3 = 0.f;
    float a4 = 0.f, a5 = 0.f, a6 = 0.f, a7 = 0.f;
#pragma unroll
    for (int s4i = 0; s4i < 4; ++s4i) {
        const int sidx = st * 4 + s4i;   // 0..63
        const float* base;
        if (sidx < nrow) {
            const int bxx = B + (sidx >> 1);
            const int t = bxx * (bxx + 1) / 2 + B;
            base = pr + ((size_t)(t * 2 + (sidx & 1)) * 128 + rl) * 8;
        } else {
            const int m = sidx - nrow;
            const int t = B * (B + 1) / 2 + (m >> 1);
            base = pc + ((size_t)(t * 2 + (m & 1)) * 128 + rl) * 8;
        }
        float4 u0 = *(const float4*)(base);
        float4 u1 = *(const float4*)(base + 4);
        a0 += u0.x; a1 += u0.y; a2 += u0.z; a3 += u0.w;
        a4 += u1.x; a5 += u1.y; a6 += u1.z; a7 += u1.w;
    }
#pragma unroll
    for (int off = 1; off < 16; off <<= 1) {
        a0 += __shfl_xor(a0, off, 64);
        a1 += __shfl_xor(a1, off, 64);
        a2 += __shfl_xor(a2, off, 64);
        a3 += __shfl_xor(a3, off, 64);
        a4 += __shfl_xor(a4, off, 64);
        a5 += __shfl_xor(a5, off, 64);
        a6 += __shfl_xor(a6, off, 64);
        a7 += __shfl_xor(a7, off, 64);
    }
    __shared__ float lred[16];
    if (st == 0) {
        const float l = a0 / (a1 + EPSV) + a2 / (a3 + EPSV)
            + (C1E * fmaf(2.4f, a5, -a4)) / (C1E * a5 + EPSV)
            + (C2E * fmaf(2.2f, a7, -a6)) / (C2E * a7 + EPSV);
        lred[rloc16] = l;
    }
    __syncthreads();
    if (tid == 0) {
        float tot = 0.f;
#pragma unroll
        for (int k2 = 0; k2 < 16; ++k2) tot += lred[k2];
        atomicAdd(out, tot / (float)N);
    }
}

// ---------------------------------------------------------------------------
// Fallback path (144 KB ws): fp32 tile GEMM + atomic epilogue (R1, known-good)
// ---------------------------------------------------------------------------
__launch_bounds__(THREADS, 2)
__global__ void dist_loss_kernel(const float* __restrict__ x,
                                 const int* __restrict__ targets,
                                 const int* __restrict__ sub,
                                 const float* __restrict__ inv_norm,
                                 float* __restrict__ acc,
                                 int N, int D) {
    __shared__ float Asf[16][128];
    __shared__ float Bsf[16][128];

    const int nbx = N / 128;
    const int bx = blockIdx.x % nbx;
    const int by = blockIdx.x / nbx;
    const int tid = threadIdx.x;
    const int tx = tid & 15;
    const int ty = tid >> 4;
    const int rowA0 = by * 128;
    const int colB0 = bx * 128;
    const float* Abase = x + (size_t)rowA0 * D;
    const float* Bbase = x + (size_t)colB0 * D;

    float accv[8][8];
#pragma unroll
    for (int r = 0; r < 8; ++r)
#pragma unroll
        for (int c = 0; c < 8; ++c) accv[r][c] = 0.f;

    for (int kb = 0; kb < D; kb += 16) {
#pragma unroll
        for (int l = 0; l < 2; ++l) {
            const int f = tid + l * THREADS;
            const int row = f >> 2;
            const int kq = (f & 3) << 2;
            float4 va = *(const float4*)(Abase + (size_t)row * D + kb + kq);
            float4 vb = *(const float4*)(Bbase + (size_t)row * D + kb + kq);
            Asf[kq + 0][row] = va.x; Asf[kq + 1][row] = va.y;
            Asf[kq + 2][row] = va.z; Asf[kq + 3][row] = va.w;
            Bsf[kq + 0][row] = vb.x; Bsf[kq + 1][row] = vb.y;
            Bsf[kq + 2][row] = vb.z; Bsf[kq + 3][row] = vb.w;
        }
        __syncthreads();
#pragma unroll
        for (int k = 0; k < 16; ++k) {
            float4 a0 = *(const float4*)&Asf[k][ty * 8];
            float4 a1 = *(const float4*)&Asf[k][ty * 8 + 4];
            float4 b0 = *(const float4*)&Bsf[k][tx * 8];
            float4 b1 = *(const float4*)&Bsf[k][tx * 8 + 4];
            float ar[8] = {a0.x, a0.y, a0.z, a0.w, a1.x, a1.y, a1.z, a1.w};
            float br[8] = {b0.x, b0.y, b0.z, b0.w, b1.x, b1.y, b1.z, b1.w};
#pragma unroll
            for (int r = 0; r < 8; ++r)
#pragma unroll
                for (int c = 0; c < 8; ++c)
                    accv[r][c] = fmaf(ar[r], br[c], accv[r][c]);
        }
        __syncthreads();
    }

    const int row_base = rowA0 + ty * 8;
    const int col_base = colB0 + tx * 8;
    int tjc[8], sjc[8];
    float invj[8];
#pragma unroll
    for (int c = 0; c < 8; ++c) {
        tjc[c] = targets[col_base + c];
        sjc[c] = sub[col_base + c];
        invj[c] = inv_norm[col_base + c];
    }
#pragma unroll
    for (int r = 0; r < 8; ++r) {
        const int gi = row_base + r;
        const int ti = targets[gi];
        const int si = sub[gi];
        const float invi = inv_norm[gi];
        float s0 = 0.f, s1 = 0.f, s2 = 0.f, s3 = 0.f;
        float s4 = 0.f, s5 = 0.f, s6 = 0.f, s7 = 0.f;
#pragma unroll
        for (int c = 0; c < 8; ++c) {
            const int gj = col_base + c;
            const float dot = accv[r][c] * invi * invj[c];
            const float dd = sqrtf(fmaxf(2.f - 2.f * dot, 1e-12f));
            const bool same = (ti == tjc[c]);
            const bool intra = (si == sjc[c]);
            const bool pos = same && (gi != gj);
            const bool neg = !same;
            const float df = (intra ? 2.4f : 2.2f) - dd;
            const float wgt = __expf(df);
            const float v = fmaxf(dd - (intra ? 1.4f : 0.7f), 0.f);
            if (pos && intra)  { s0 += v; s1 += 1.f; }
            if (pos && !intra) { s2 += v; s3 += 1.f; }
            if (neg && intra)  { s4 += df * wgt; s5 += wgt; }
            if (neg && !intra) { s6 += df * wgt; s7 += wgt; }
        }
#pragma unroll
        for (int off = 1; off < 16; off <<= 1) {
            s0 += __shfl_xor(s0, off, 64);
            s1 += __shfl_xor(s1, off, 64);
            s2 += __shfl_xor(s2, off, 64);
            s3 += __shfl_xor(s3, off, 64);
            s4 += __shfl_xor(s4, off, 64);
            s5 += __shfl_xor(s5, off, 64);
            s6 += __shfl_xor(s6, off, 64);
            s7 += __shfl_xor(s7, off, 64);
        }
        if (tx == 0) {
            float* a = acc + (size_t)gi * 8;
            atomicAdd(a + 0, s0); atomicAdd(a + 1, s1);
            atomicAdd(a + 2, s2); atomicAdd(a + 3, s3);
            atomicAdd(a + 4, s4); atomicAdd(a + 5, s5);
            atomicAdd(a + 6, s6); atomicAdd(a + 7, s7);
        }
    }
}

__global__ void finalize_kernel(const float* __restrict__ acc,
                                float* __restrict__ out, int N) {
    float s = 0.f;
    for (int i = threadIdx.x; i < N; i += THREADS) {
        const float* a = acc + (size_t)i * 8;
        s += a[0] / (a[1] + EPSV) + a[2] / (a[3] + EPSV)
           + a[4] / (a[5] + EPSV) + a[6] / (a[7] + EPSV);
    }
#pragma unroll
    for (int off = 32; off > 0; off >>= 1) s += __shfl_down(s, off, 64);
    __shared__ float red[THREADS / 64];
    if ((threadIdx.x & 63) == 0) red[threadIdx.x >> 6] = s;
    __syncthreads();
    if (threadIdx.x == 0) {
        float tot = 0.f;
#pragma unroll
        for (int w = 0; w < THREADS / 64; ++w) tot += red[w];
        out[0] = tot / (float)N;
    }
}

// ---------------------------------------------------------------------------
extern "C" void kernel_launch(void* const* d_in, const int* in_sizes, int n_in,
                              void* d_out, int out_size, void* d_ws, size_t ws_size,
                              hipStream_t stream) {
    const float* x = (const float*)d_in[0];
    const int* targets = (const int*)d_in[1];
    const int* sub = (const int*)d_in[2];
    const int N = in_sizes[1];
    const int D = in_sizes[0] / N;

    const int nbx = N / BM;
    const int T = nbx * (nbx + 1) / 2;
    const size_t sliceB = (size_t)T * 2 * 128 * 8 * sizeof(float);
    const size_t need = (size_t)N * 4 + (size_t)N * D * 2 + 2 * sliceB;

    if (ws_size >= need) {
        float* inv_norm = (float*)d_ws;                       // N floats
        unsigned short* xb = (unsigned short*)(inv_norm + N); // N*D bf16
        float* pr = (float*)((char*)d_ws + (size_t)N * 4 + (size_t)N * D * 2);
        float* pc = pr + (size_t)T * 2 * 128 * 8;

        hipMemsetAsync(d_out, 0, sizeof(float), stream);
        conv_norm_kernel<<<N, THREADS, 0, stream>>>(x, xb, inv_norm, D);
        gram_sym_kernel<<<T, THREADS, 0, stream>>>(xb, targets, sub,
                                                   inv_norm, pr, pc, D);
        finalize_sym_kernel<<<N / 16, THREADS, 0, stream>>>(
            pr, pc, (float*)d_out, N, nbx);
    } else {
        // Fallback (144 KB ws): fp32 path, known-good from round 1.
        float* inv_norm = (float*)d_ws;
        float* acc = inv_norm + N;
        hipMemsetAsync(acc, 0, (size_t)N * 8 * sizeof(float), stream);
        row_inv_norm_kernel<<<N, THREADS, 0, stream>>>(x, inv_norm, D);
        dist_loss_kernel<<<nbx * nbx, THREADS, 0, stream>>>(
            x, targets, sub, inv_norm, acc, N, D);
        finalize_kernel<<<1, THREADS, 0, stream>>>(acc, (float*)d_out, N);
    }
}

// Round 11
// 195.915 us; speedup vs baseline: 1.2336x; 1.0132x over previous
//
#include <hip/hip_runtime.h>
#include <math.h>

#define THREADS 256
#define BM 128
#define BK 32
#define EPSV 1e-5f
#define C1E 11.023176380641601f   // e^2.4
#define C2E 9.025013499434122f    // e^2.2

typedef short bf16x8 __attribute__((ext_vector_type(8)));   // 8 bf16 = 16 B
typedef float f32x4 __attribute__((ext_vector_type(4)));

// RNE float -> bf16 bit pattern
__device__ __forceinline__ unsigned short f2bf(float f) {
    unsigned int u = __float_as_uint(f);
    u += 0x7FFFu + ((u >> 16) & 1u);
    return (unsigned short)(u >> 16);
}

#define GLDS16(g, l)                                                          \
    __builtin_amdgcn_global_load_lds(                                         \
        (const __attribute__((address_space(1))) unsigned int*)(g),           \
        (__attribute__((address_space(3))) unsigned int*)(l), 16, 0, 0)

// ---------------------------------------------------------------------------
// Kernel A (sym path): NORMALIZE + convert. xb[row] = bf16(x[row]/||x[row]||).
// Two-phase: sum-of-squares -> LDS broadcast -> scale+convert with 16B/lane
// stores (R10's conv used 8B stores; suspected source of the ~70us gap).
// Normalization folded into xb => gram epilogue needs no inv_norm at all.
// ---------------------------------------------------------------------------
__launch_bounds__(THREADS)
__global__ void norm_conv_kernel(const float* __restrict__ x,
                                 unsigned short* __restrict__ xb, int D) {
    const int row = blockIdx.x;
    const float4* x4 = (const float4*)(x + (size_t)row * D);
    const int tid = threadIdx.x;

    // Phase 1: sum of squares (each thread: 8 consecutive floats per iter).
    float s = 0.f;
    for (int b = tid * 2; b * 4 < D; b += THREADS * 2) {
        float4 v0 = x4[b];
        float4 v1 = x4[b + 1];
        s += v0.x * v0.x + v0.y * v0.y + v0.z * v0.z + v0.w * v0.w
           + v1.x * v1.x + v1.y * v1.y + v1.z * v1.z + v1.w * v1.w;
    }
#pragma unroll
    for (int off = 32; off > 0; off >>= 1) s += __shfl_down(s, off, 64);
    __shared__ float red[THREADS / 64 + 1];
    if ((tid & 63) == 0) red[tid >> 6] = s;
    __syncthreads();
    if (tid == 0) {
        float tot = 0.f;
#pragma unroll
        for (int w = 0; w < THREADS / 64; ++w) tot += red[w];
        red[THREADS / 64] = 1.0f / fmaxf(sqrtf(tot), 1e-12f);
    }
    __syncthreads();
    const float inv = red[THREADS / 64];

    // Phase 2: re-read (L1/L2-hot), scale, convert, 16B/lane store.
    bf16x8* out8 = (bf16x8*)(xb + (size_t)row * D);
    for (int b = tid * 2; b * 4 < D; b += THREADS * 2) {
        float4 v0 = x4[b];
        float4 v1 = x4[b + 1];
        bf16x8 o;
        o[0] = (short)f2bf(v0.x * inv); o[1] = (short)f2bf(v0.y * inv);
        o[2] = (short)f2bf(v0.z * inv); o[3] = (short)f2bf(v0.w * inv);
        o[4] = (short)f2bf(v1.x * inv); o[5] = (short)f2bf(v1.y * inv);
        o[6] = (short)f2bf(v1.z * inv); o[7] = (short)f2bf(v1.w * inv);
        out8[b >> 1] = o;
    }
}

// Plain inv-norm (fallback path).
__global__ void row_inv_norm_kernel(const float* __restrict__ x,
                                    float* __restrict__ inv_norm, int D) {
    const int row = blockIdx.x;
    const float4* x4 = (const float4*)(x + (size_t)row * D);
    const int nf4 = D >> 2;
    float s = 0.f;
    for (int i = threadIdx.x; i < nf4; i += THREADS) {
        float4 v = x4[i];
        s += v.x * v.x + v.y * v.y + v.z * v.z + v.w * v.w;
    }
#pragma unroll
    for (int off = 32; off > 0; off >>= 1) s += __shfl_down(s, off, 64);
    __shared__ float red[THREADS / 64];
    if ((threadIdx.x & 63) == 0) red[threadIdx.x >> 6] = s;
    __syncthreads();
    if (threadIdx.x == 0) {
        float tot = 0.f;
#pragma unroll
        for (int w = 0; w < THREADS / 64; ++w) tot += red[w];
        inv_norm[row] = 1.0f / fmaxf(sqrtf(tot), 1e-12f);
    }
}

// ---------------------------------------------------------------------------
// Kernel B: SYMMETRIC bf16 Gram tile + two-pass epilogue. K-loop = R10's
// double-buffered glds pipeline (measured identical to R8 single-buffer; kept).
// xb is pre-normalized => d^2 = 2 - 2*dot directly, no inv_norm traffic.
// vals: 0 s_pos_intra 1 cnt_pi 2 s_pos_cross 3 cnt_pc
//       4 DE_neg_intra 5 E_neg_intra 6 DE_neg_cross 7 E_neg_cross
//       (E = sum exp(-d), DE = sum d*exp(-d); e^alpha folded in finalize)
// ---------------------------------------------------------------------------
__launch_bounds__(THREADS, 2)
__global__ void gram_sym_kernel(const unsigned short* __restrict__ xb,
                                const int* __restrict__ targets,
                                const int* __restrict__ sub,
                                float* __restrict__ pr,
                                float* __restrict__ pc,
                                int D) {
    __shared__ unsigned short As[2][BM * BK];   // 2 x 8 KB
    __shared__ unsigned short Bs[2][BM * BK];   // 2 x 8 KB

    // Triangular decode: tk = bx*(bx+1)/2 + by, by <= bx.
    const int tk = blockIdx.x;
    int bx = (int)((sqrtf(8.0f * tk + 1.0f) - 1.0f) * 0.5f);
    while ((bx + 1) * (bx + 2) / 2 <= tk) ++bx;
    while (bx * (bx + 1) / 2 > tk) --bx;
    const int by = tk - bx * (bx + 1) / 2;

    const int tid = threadIdx.x;
    const int w = tid >> 6;          // wave 0..3
    const int lane = tid & 63;
    const int wm = w & 1;            // row-half
    const int wn = w >> 1;           // col-half
    const int quad = lane >> 4;
    const int cl = lane & 15;

    const int rowA0 = by * BM;
    const int colB0 = bx * BM;
    const unsigned short* Abase = xb + (size_t)rowA0 * D;
    const unsigned short* Bbase = xb + (size_t)colB0 * D;

    // glds staging: 512 chunks of 16B per tile. Wave w, issue l covers LDS
    // chunks (l*256 + w*64 + lane); source chunk index is XOR-swizzled.
    const int ca0 = w * 64 + lane;
    const int ca1 = 256 + w * 64 + lane;
    const int r0 = ca0 >> 2, q0 = (ca0 & 3) ^ ((r0 >> 1) & 3);
    const int r1 = ca1 >> 2, q1 = (ca1 & 3) ^ ((r1 >> 1) & 3);
    const unsigned short* sA0 = Abase + (size_t)r0 * D + q0 * 8;
    const unsigned short* sA1 = Abase + (size_t)r1 * D + q1 * 8;
    const unsigned short* sB0 = Bbase + (size_t)r0 * D + q0 * 8;
    const unsigned short* sB1 = Bbase + (size_t)r1 * D + q1 * 8;
    const int dof0 = (w * 64) * 8;            // wave-uniform LDS offsets
    const int dof1 = (256 + w * 64) * 8;

    f32x4 accv[4][4];
#pragma unroll
    for (int i = 0; i < 4; ++i)
#pragma unroll
        for (int j = 0; j < 4; ++j) accv[i][j] = (f32x4)(0.f);

    // Fragment read offsets (tile-local), swizzled: q' = quad ^ ((row>>1)&3).
    int aoff[4], boff[4];
#pragma unroll
    for (int f = 0; f < 4; ++f) {
        const int ar = wm * 64 + f * 16 + cl;
        aoff[f] = ar * BK + (quad ^ ((ar >> 1) & 3)) * 8;
        const int br = wn * 64 + f * 16 + cl;
        boff[f] = br * BK + (quad ^ ((br >> 1) & 3)) * 8;
    }

    const int nIter = D / BK;

    // Prologue: stage tile 0 into buf 0.
    GLDS16(sA0, &As[0][dof0]);
    GLDS16(sA1, &As[0][dof1]);
    GLDS16(sB0, &Bs[0][dof0]);
    GLDS16(sB1, &Bs[0][dof1]);
    __syncthreads();

    for (int it = 0; it < nIter; ++it) {
        const int cur = it & 1;
        const int nxt = cur ^ 1;

        if (it + 1 < nIter) {
            const int kb = (it + 1) * BK;
            GLDS16(sA0 + kb, &As[nxt][dof0]);
            GLDS16(sA1 + kb, &As[nxt][dof1]);
            GLDS16(sB0 + kb, &Bs[nxt][dof0]);
            GLDS16(sB1 + kb, &Bs[nxt][dof1]);
        }

        bf16x8 af[4], bfv[4];
#pragma unroll
        for (int f = 0; f < 4; ++f) {
            af[f] = *(const bf16x8*)&As[cur][aoff[f]];
            bfv[f] = *(const bf16x8*)&Bs[cur][boff[f]];
        }
#pragma unroll
        for (int mi = 0; mi < 4; ++mi)
#pragma unroll
            for (int ni = 0; ni < 4; ++ni)
                accv[mi][ni] = __builtin_amdgcn_mfma_f32_16x16x32_bf16(
                    af[mi], bfv[ni], accv[mi][ni], 0, 0, 0);

        __syncthreads();
    }

    // ---------------- epilogue pass 1: dd + row partials ----------------
    // C/D map: col = cl, row = quad*4 + reg.
    int tj[4], sj[4];
#pragma unroll
    for (int ni = 0; ni < 4; ++ni) {
        const int gc = colB0 + wn * 64 + ni * 16 + cl;
        tj[ni] = targets[gc];
        sj[ni] = sub[gc];
    }

#pragma unroll
    for (int mi = 0; mi < 4; ++mi) {
#pragma unroll
        for (int r = 0; r < 4; ++r) {
            const int gi = rowA0 + wm * 64 + mi * 16 + quad * 4 + r;
            const int ti = targets[gi];
            const int si = sub[gi];

            float s0 = 0.f, s1 = 0.f, s2 = 0.f, s3 = 0.f;
            float s4 = 0.f, s5 = 0.f, s6 = 0.f, s7 = 0.f;
#pragma unroll
            for (int ni = 0; ni < 4; ++ni) {
                const int gj = colB0 + wn * 64 + ni * 16 + cl;
                const float d2 = fmaf(-2.f, accv[mi][ni][r], 2.f);
                const float dd = sqrtf(fmaxf(d2, 1e-12f));
                accv[mi][ni][r] = dd;          // overwrite: pass 2 reuses
                const bool same = (ti == tj[ni]);
                const bool intra = (si == sj[ni]);
                const bool pos = same && (gi != gj);
                const bool neg = !same;
                const float mg = intra ? 1.4f : 0.7f;
                const float v = fmaxf(dd - mg, 0.f);
                const float e = __expf(-dd);   // e^alpha folded in finalize
                const float de = dd * e;
                if (pos && intra)  { s0 += v;  s1 += 1.f; }
                if (pos && !intra) { s2 += v;  s3 += 1.f; }
                if (neg && intra)  { s4 += de; s5 += e; }
                if (neg && !intra) { s6 += de; s7 += e; }
            }
#pragma unroll
            for (int off = 1; off < 16; off <<= 1) {
                s0 += __shfl_xor(s0, off, 64);
                s1 += __shfl_xor(s1, off, 64);
                s2 += __shfl_xor(s2, off, 64);
                s3 += __shfl_xor(s3, off, 64);
                s4 += __shfl_xor(s4, off, 64);
                s5 += __shfl_xor(s5, off, 64);
                s6 += __shfl_xor(s6, off, 64);
                s7 += __shfl_xor(s7, off, 64);
            }
            if (cl == 0) {
                const int rloc = wm * 64 + mi * 16 + quad * 4 + r;
                float* dst = pr +
                    ((size_t)(blockIdx.x * 2 + wn) * 128 + rloc) * 8;
                float4 p0 = {s0, s1, s2, s3};
                float4 p1 = {s4, s5, s6, s7};
                *(float4*)(dst) = p0;
                *(float4*)(dst + 4) = p1;
            }
        }
    }

    // ---------------- epilogue pass 2: col partials ----------------
    const float om = (bx == by) ? 0.f : 1.f;   // diag tiles: zero col side
#pragma unroll
    for (int ni = 0; ni < 4; ++ni) {
        const int gj = colB0 + wn * 64 + ni * 16 + cl;
        const int tjc = tj[ni];
        const int sjc = sj[ni];
        float s0 = 0.f, s1 = 0.f, s2 = 0.f, s3 = 0.f;
        float s4 = 0.f, s5 = 0.f, s6 = 0.f, s7 = 0.f;
#pragma unroll
        for (int mi = 0; mi < 4; ++mi) {
#pragma unroll
            for (int r = 0; r < 4; ++r) {
                const int gi = rowA0 + wm * 64 + mi * 16 + quad * 4 + r;
                const int ti = targets[gi];     // L1-hot reload
                const int si = sub[gi];
                const float dd = accv[mi][ni][r];
                const bool same = (ti == tjc);
                const bool intra = (si == sjc);
                const bool pos = same && (gi != gj);
                const bool neg = !same;
                const float mg = intra ? 1.4f : 0.7f;
                const float v = fmaxf(dd - mg, 0.f);
                const float e = __expf(-dd);
                const float de = dd * e;
                if (pos && intra)  { s0 += v;  s1 += 1.f; }
                if (pos && !intra) { s2 += v;  s3 += 1.f; }
                if (neg && intra)  { s4 += de; s5 += e; }
                if (neg && !intra) { s6 += de; s7 += e; }
            }
        }
        // Reduce over the 4 quads (row groups): lanes differing in bits 4,5.
        s0 += __shfl_xor(s0, 16, 64); s0 += __shfl_xor(s0, 32, 64);
        s1 += __shfl_xor(s1, 16, 64); s1 += __shfl_xor(s1, 32, 64);
        s2 += __shfl_xor(s2, 16, 64); s2 += __shfl_xor(s2, 32, 64);
        s3 += __shfl_xor(s3, 16, 64); s3 += __shfl_xor(s3, 32, 64);
        s4 += __shfl_xor(s4, 16, 64); s4 += __shfl_xor(s4, 32, 64);
        s5 += __shfl_xor(s5, 16, 64); s5 += __shfl_xor(s5, 32, 64);
        s6 += __shfl_xor(s6, 16, 64); s6 += __shfl_xor(s6, 32, 64);
        s7 += __shfl_xor(s7, 16, 64); s7 += __shfl_xor(s7, 32, 64);
        if (lane < 16) {
            const int colloc = wn * 64 + ni * 16 + lane;
            float* dst = pc +
                ((size_t)(blockIdx.x * 2 + wm) * 128 + colloc) * 8;
            float4 p0 = {s0 * om, s1 * om, s2 * om, s3 * om};
            float4 p1 = {s4 * om, s5 * om, s6 * om, s7 * om};
            *(float4*)(dst) = p0;
            *(float4*)(dst + 4) = p1;
        }
    }
}

// ---------------------------------------------------------------------------
// Kernel C: gather 64 slices per row, combine ratios, global mean.
// Block = 16 rows x 16 slice-threads.
// ---------------------------------------------------------------------------
__global__ void finalize_sym_kernel(const float* __restrict__ pr,
                                    const float* __restrict__ pc,
                                    float* __restrict__ out, int N, int nbx) {
    const int tid = threadIdx.x;
    const int rloc16 = tid >> 4;   // row within block, 0..15
    const int st = tid & 15;       // slice-thread
    const int i = blockIdx.x * 16 + rloc16;
    const int B = i >> 7;          // row's 128-block
    const int rl = i & 127;
    const int nrow = (nbx - B) * 2;   // # row-side slices

    float a0 = 0.f, a1 = 0.f, a2 = 0.f, a3 = 0.f;
    float a4 = 0.f, a5 = 0.f, a6 = 0.f, a7 = 0.f;
#pragma unroll
    for (int s4i = 0; s4i < 4; ++s4i) {
        const int sidx = st * 4 + s4i;   // 0..63
        const float* base;
        if (sidx < nrow) {
            const int bxx = B + (sidx >> 1);
            const int t = bxx * (bxx + 1) / 2 + B;
            base = pr + ((size_t)(t * 2 + (sidx & 1)) * 128 + rl) * 8;
        } else {
            const int m = sidx - nrow;
            const int t = B * (B + 1) / 2 + (m >> 1);
            base = pc + ((size_t)(t * 2 + (m & 1)) * 128 + rl) * 8;
        }
        float4 u0 = *(const float4*)(base);
        float4 u1 = *(const float4*)(base + 4);
        a0 += u0.x; a1 += u0.y; a2 += u0.z; a3 += u0.w;
        a4 += u1.x; a5 += u1.y; a6 += u1.z; a7 += u1.w;
    }
#pragma unroll
    for (int off = 1; off < 16; off <<= 1) {
        a0 += __shfl_xor(a0, off, 64);
        a1 += __shfl_xor(a1, off, 64);
        a2 += __shfl_xor(a2, off, 64);
        a3 += __shfl_xor(a3, off, 64);
        a4 += __shfl_xor(a4, off, 64);
        a5 += __shfl_xor(a5, off, 64);
        a6 += __shfl_xor(a6, off, 64);
        a7 += __shfl_xor(a7, off, 64);
    }
    __shared__ float lred[16];
    if (st == 0) {
        const float l = a0 / (a1 + EPSV) + a2 / (a3 + EPSV)
            + (C1E * fmaf(2.4f, a5, -a4)) / (C1E * a5 + EPSV)
            + (C2E * fmaf(2.2f, a7, -a6)) / (C2E * a7 + EPSV);
        lred[rloc16] = l;
    }
    __syncthreads();
    if (tid == 0) {
        float tot = 0.f;
#pragma unroll
        for (int k2 = 0; k2 < 16; ++k2) tot += lred[k2];
        atomicAdd(out, tot / (float)N);
    }
}

// ---------------------------------------------------------------------------
// Fallback path (144 KB ws): fp32 tile GEMM + atomic epilogue (R1, known-good)
// ---------------------------------------------------------------------------
__launch_bounds__(THREADS, 2)
__global__ void dist_loss_kernel(const float* __restrict__ x,
                                 const int* __restrict__ targets,
                                 const int* __restrict__ sub,
                                 const float* __restrict__ inv_norm,
                                 float* __restrict__ acc,
                                 int N, int D) {
    __shared__ float Asf[16][128];
    __shared__ float Bsf[16][128];

    const int nbx = N / 128;
    const int bx = blockIdx.x % nbx;
    const int by = blockIdx.x / nbx;
    const int tid = threadIdx.x;
    const int tx = tid & 15;
    const int ty = tid >> 4;
    const int rowA0 = by * 128;
    const int colB0 = bx * 128;
    const float* Abase = x + (size_t)rowA0 * D;
    const float* Bbase = x + (size_t)colB0 * D;

    float accv[8][8];
#pragma unroll
    for (int r = 0; r < 8; ++r)
#pragma unroll
        for (int c = 0; c < 8; ++c) accv[r][c] = 0.f;

    for (int kb = 0; kb < D; kb += 16) {
#pragma unroll
        for (int l = 0; l < 2; ++l) {
            const int f = tid + l * THREADS;
            const int row = f >> 2;
            const int kq = (f & 3) << 2;
            float4 va = *(const float4*)(Abase + (size_t)row * D + kb + kq);
            float4 vb = *(const float4*)(Bbase + (size_t)row * D + kb + kq);
            Asf[kq + 0][row] = va.x; Asf[kq + 1][row] = va.y;
            Asf[kq + 2][row] = va.z; Asf[kq + 3][row] = va.w;
            Bsf[kq + 0][row] = vb.x; Bsf[kq + 1][row] = vb.y;
            Bsf[kq + 2][row] = vb.z; Bsf[kq + 3][row] = vb.w;
        }
        __syncthreads();
#pragma unroll
        for (int k = 0; k < 16; ++k) {
            float4 a0 = *(const float4*)&Asf[k][ty * 8];
            float4 a1 = *(const float4*)&Asf[k][ty * 8 + 4];
            float4 b0 = *(const float4*)&Bsf[k][tx * 8];
            float4 b1 = *(const float4*)&Bsf[k][tx * 8 + 4];
            float ar[8] = {a0.x, a0.y, a0.z, a0.w, a1.x, a1.y, a1.z, a1.w};
            float br[8] = {b0.x, b0.y, b0.z, b0.w, b1.x, b1.y, b1.z, b1.w};
#pragma unroll
            for (int r = 0; r < 8; ++r)
#pragma unroll
                for (int c = 0; c < 8; ++c)
                    accv[r][c] = fmaf(ar[r], br[c], accv[r][c]);
        }
        __syncthreads();
    }

    const int row_base = rowA0 + ty * 8;
    const int col_base = colB0 + tx * 8;
    int tjc[8], sjc[8];
    float invj[8];
#pragma unroll
    for (int c = 0; c < 8; ++c) {
        tjc[c] = targets[col_base + c];
        sjc[c] = sub[col_base + c];
        invj[c] = inv_norm[col_base + c];
    }
#pragma unroll
    for (int r = 0; r < 8; ++r) {
        const int gi = row_base + r;
        const int ti = targets[gi];
        const int si = sub[gi];
        const float invi = inv_norm[gi];
        float s0 = 0.f, s1 = 0.f, s2 = 0.f, s3 = 0.f;
        float s4 = 0.f, s5 = 0.f, s6 = 0.f, s7 = 0.f;
#pragma unroll
        for (int c = 0; c < 8; ++c) {
            const int gj = col_base + c;
            const float dot = accv[r][c] * invi * invj[c];
            const float dd = sqrtf(fmaxf(2.f - 2.f * dot, 1e-12f));
            const bool same = (ti == tjc[c]);
            const bool intra = (si == sjc[c]);
            const bool pos = same && (gi != gj);
            const bool neg = !same;
            const float df = (intra ? 2.4f : 2.2f) - dd;
            const float wgt = __expf(df);
            const float v = fmaxf(dd - (intra ? 1.4f : 0.7f), 0.f);
            if (pos && intra)  { s0 += v; s1 += 1.f; }
            if (pos && !intra) { s2 += v; s3 += 1.f; }
            if (neg && intra)  { s4 += df * wgt; s5 += wgt; }
            if (neg && !intra) { s6 += df * wgt; s7 += wgt; }
        }
#pragma unroll
        for (int off = 1; off < 16; off <<= 1) {
            s0 += __shfl_xor(s0, off, 64);
            s1 += __shfl_xor(s1, off, 64);
            s2 += __shfl_xor(s2, off, 64);
            s3 += __shfl_xor(s3, off, 64);
            s4 += __shfl_xor(s4, off, 64);
            s5 += __shfl_xor(s5, off, 64);
            s6 += __shfl_xor(s6, off, 64);
            s7 += __shfl_xor(s7, off, 64);
        }
        if (tx == 0) {
            float* a = acc + (size_t)gi * 8;
            atomicAdd(a + 0, s0); atomicAdd(a + 1, s1);
            atomicAdd(a + 2, s2); atomicAdd(a + 3, s3);
            atomicAdd(a + 4, s4); atomicAdd(a + 5, s5);
            atomicAdd(a + 6, s6); atomicAdd(a + 7, s7);
        }
    }
}

__global__ void finalize_kernel(const float* __restrict__ acc,
                                float* __restrict__ out, int N) {
    float s = 0.f;
    for (int i = threadIdx.x; i < N; i += THREADS) {
        const float* a = acc + (size_t)i * 8;
        s += a[0] / (a[1] + EPSV) + a[2] / (a[3] + EPSV)
           + a[4] / (a[5] + EPSV) + a[6] / (a[7] + EPSV);
    }
#pragma unroll
    for (int off = 32; off > 0; off >>= 1) s += __shfl_down(s, off, 64);
    __shared__ float red[THREADS / 64];
    if ((threadIdx.x & 63) == 0) red[threadIdx.x >> 6] = s;
    __syncthreads();
    if (threadIdx.x == 0) {
        float tot = 0.f;
#pragma unroll
        for (int w = 0; w < THREADS / 64; ++w) tot += red[w];
        out[0] = tot / (float)N;
    }
}

// ---------------------------------------------------------------------------
extern "C" void kernel_launch(void* const* d_in, const int* in_sizes, int n_in,
                              void* d_out, int out_size, void* d_ws, size_t ws_size,
                              hipStream_t stream) {
    const float* x = (const float*)d_in[0];
    const int* targets = (const int*)d_in[1];
    const int* sub = (const int*)d_in[2];
    const int N = in_sizes[1];
    const int D = in_sizes[0] / N;

    const int nbx = N / BM;
    const int T = nbx * (nbx + 1) / 2;
    const size_t sliceB = (size_t)T * 2 * 128 * 8 * sizeof(float);
    const size_t need = (size_t)N * D * 2 + 2 * sliceB;

    if (ws_size >= need) {
        unsigned short* xb = (unsigned short*)d_ws;           // N*D bf16
        float* pr = (float*)((char*)d_ws + (size_t)N * D * 2);
        float* pc = pr + (size_t)T * 2 * 128 * 8;

        hipMemsetAsync(d_out, 0, sizeof(float), stream);
        norm_conv_kernel<<<N, THREADS, 0, stream>>>(x, xb, D);
        gram_sym_kernel<<<T, THREADS, 0, stream>>>(xb, targets, sub,
                                                   pr, pc, D);
        finalize_sym_kernel<<<N / 16, THREADS, 0, stream>>>(
            pr, pc, (float*)d_out, N, nbx);
    } else {
        // Fallback (144 KB ws): fp32 path, known-good from round 1.
        float* inv_norm = (float*)d_ws;
        float* acc = inv_norm + N;
        hipMemsetAsync(acc, 0, (size_t)N * 8 * sizeof(float), stream);
        row_inv_norm_kernel<<<N, THREADS, 0, stream>>>(x, inv_norm, D);
        dist_loss_kernel<<<nbx * nbx, THREADS, 0, stream>>>(
            x, targets, sub, inv_norm, acc, N, D);
        finalize_kernel<<<1, THREADS, 0, stream>>>(acc, (float*)d_out, N);
    }
}